// Round 20
// baseline (157.091 us; speedup 1.0000x reference)
//
#include <hip/hip_runtime.h>
#include <stdint.h>

#define D_    512
#define H_    2
#define HD_   256
#define B_    16
#define S_    1194
#define MTOK  19104          // B_*S_  (even; batch boundaries at even i)
#define MPAD  19200          // 150*128
#define SPAD  1216           // 19*64 = 38*32
#define NQKV  1536
#define NKT   38             // kv tiles of 32 (global layout granularity)
#define QSPLIT 10            // attn: qt >= QSPLIT blocks are kv-split in two
#define NSQT  9              // 19 - QSPLIT
#define NSROW 18432          // 32 bh * NSQT * 64 rows
#define LOG2E 1.44269504088896340736f

typedef unsigned short u16;
typedef unsigned int u32;
typedef __attribute__((ext_vector_type(8))) short bf16x8;   // 8 bf16 = 4 VGPR
typedef __attribute__((ext_vector_type(4))) float f32x4;

__device__ inline u16 f2bf(float x) {
  union { float f; unsigned u; } c; c.f = x;
  unsigned r = c.u + 0x7fffu + ((c.u >> 16) & 1u);  // RNE
  return (u16)(r >> 16);
}
__device__ inline float bf2f(u16 v) {
  union { unsigned u; float f; } c; c.u = ((u32)v) << 16; return c.f;
}

// async global->LDS, 16B per lane. LDS dest is wave-uniform base (HW adds
// lane*16); global src per-lane, CONTIGUOUS: 1 instr = 1KB sequential.
__device__ inline void async_copy16(void* lds, const void* g) {
  __builtin_amdgcn_global_load_lds(
      (__attribute__((address_space(1))) void*)(g),
      (__attribute__((address_space(3))) void*)(lds),
      16, 0, 0);
}

// ---------------------------------------------------------------------------
// Kernel 1 (unchanged): X/W -> frag-major bf16.
// ---------------------------------------------------------------------------
__global__ void convert_kernel(const float* __restrict__ X,
                               const float* __restrict__ Wqkv,
                               const float* __restrict__ Wout,
                               u16* __restrict__ Xf,
                               u16* __restrict__ Wqf,
                               u16* __restrict__ Wof) {
  const int NXG = MPAD * 64;
  const int NQG = 12 * 8 * 16 * 64;
  const int NOG = 4 * 8 * 16 * 64;
  const int TOT = NXG + NQG + NOG;
  int stride = gridDim.x * blockDim.x;
  for (int g = blockIdx.x * blockDim.x + threadIdx.x; g < TOT; g += stride) {
    if (g < NXG) {
      int lane = g & 63, f = (g >> 6) & 15, kt = (g >> 10) & 7, mt = g >> 13;
      int i = mt * 128 + (f & 7) * 16 + (lane & 15);
      int k = kt * 64 + (f >> 3) * 32 + (lane >> 4) * 8;
      bf16x8 o;
      if (i < MTOK) {
        f32x4 v0 = *(const f32x4*)&X[(size_t)i * 512 + k];
        f32x4 v1 = *(const f32x4*)&X[(size_t)i * 512 + k + 4];
#pragma unroll
        for (int e = 0; e < 4; ++e) { o[e] = (short)f2bf(v0[e]); o[4 + e] = (short)f2bf(v1[e]); }
      } else {
#pragma unroll
        for (int e = 0; e < 8; ++e) o[e] = 0;
      }
      *(bf16x8*)&Xf[(size_t)g * 8] = o;
    } else if (g < NXG + NQG) {
      int gg = g - NXG;
      int lane = gg & 63, f = (gg >> 6) & 15, kt = (gg >> 10) & 7, nt = gg >> 13;
      int j = nt * 128 + (f & 7) * 16 + (lane & 15);
      int k = kt * 64 + (f >> 3) * 32 + (lane >> 4) * 8;
      bf16x8 o;
#pragma unroll
      for (int e = 0; e < 8; ++e) o[e] = (short)f2bf(Wqkv[(size_t)(k + e) * NQKV + j]);
      *(bf16x8*)&Wqf[(size_t)gg * 8] = o;
    } else {
      int gg = g - NXG - NQG;
      int lane = gg & 63, f = (gg >> 6) & 15, kt = (gg >> 10) & 7, nt = gg >> 13;
      int j = nt * 128 + (f & 7) * 16 + (lane & 15);
      int k = kt * 64 + (f >> 3) * 32 + (lane >> 4) * 8;
      bf16x8 o;
#pragma unroll
      for (int e = 0; e < 8; ++e) o[e] = (short)f2bf(Wout[(size_t)(k + e) * 512 + j]);
      *(bf16x8*)&Wof[(size_t)gg * 8] = o;
    }
  }
}

// ---------------------------------------------------------------------------
// GEMM v3 (unchanged): m97 single-buffer schedule + vectorized epilogue.
// ---------------------------------------------------------------------------
template<int MODE>
__global__ __launch_bounds__(256, 2) void gemm_kernel(
    const u16* __restrict__ Af, const u16* __restrict__ Bf,
    const float* __restrict__ bias, int nb,
    u16* __restrict__ Qb, u16* __restrict__ Kf, u16* __restrict__ Vf,
    float* __restrict__ Cout)
{
  __shared__ u16 ldsA[16 * 512];
  __shared__ u16 ldsB[16 * 512];

  const int t  = threadIdx.x;
  const int l  = t & 63;
  const int w  = t >> 6;
  const int lr = l >> 4, lc = l & 15;

  const int nwg = gridDim.x;
  const int qq = nwg >> 3, rr8 = nwg & 7;
  const int xcd = blockIdx.x & 7, off = blockIdx.x >> 3;
  const int wgid = (xcd < rr8 ? xcd * (qq + 1) : rr8 * (qq + 1) + (xcd - rr8) * qq) + off;
  const int m0 = (wgid / nb) * 128;
  const int n0 = (wgid % nb) * 128;
  const bool vband = (MODE == 0) && ((wgid % nb) >= 8);

  const u16* pA = Af + ((size_t)(m0 >> 7) * 128 + w) * 512 + l * 8;
  const u16* pB = Bf + ((size_t)(n0 >> 7) * 128 + w) * 512 + l * 8;

  f32x4 acc[4][4] = {};

  for (int kt = 0; kt < 8; ++kt) {
    __syncthreads();
    const u16* qA = pA + kt * 8192;
    const u16* qB = pB + kt * 8192;
#pragma unroll
    for (int c = 0; c < 4; ++c) {
      async_copy16(&ldsA[(c * 4 + w) * 512], qA + c * 2048);
      async_copy16(&ldsB[(c * 4 + w) * 512], qB + c * 2048);
    }
    __syncthreads();
#pragma unroll
    for (int kk = 0; kk < 2; ++kk) {
      bf16x8 af[4], bfr[4];
#pragma unroll
      for (int m = 0; m < 4; ++m)
        af[m] = *(bf16x8*)&ldsA[((kk * 8 + (w >> 1) * 4 + m) * 64 + l) * 8];
#pragma unroll
      for (int n = 0; n < 4; ++n)
        bfr[n] = *(bf16x8*)&ldsB[((kk * 8 + (w & 1) * 4 + n) * 64 + l) * 8];
      __builtin_amdgcn_s_setprio(1);
      if (!vband) {
#pragma unroll
        for (int m = 0; m < 4; ++m)
#pragma unroll
          for (int n = 0; n < 4; ++n)
            acc[m][n] = __builtin_amdgcn_mfma_f32_16x16x32_bf16(bfr[n], af[m], acc[m][n], 0, 0, 0);
      } else {
#pragma unroll
        for (int m = 0; m < 4; ++m)
#pragma unroll
          for (int n = 0; n < 4; ++n)
            acc[m][n] = __builtin_amdgcn_mfma_f32_16x16x32_bf16(af[m], bfr[n], acc[m][n], 0, 0, 0);
      }
      __builtin_amdgcn_s_setprio(0);
    }
  }

  if (MODE == 1) {
#pragma unroll
    for (int m = 0; m < 4; ++m) {
      int i = m0 + (w >> 1) * 64 + m * 16 + lc;
      if (i >= MTOK) continue;
#pragma unroll
      for (int n = 0; n < 4; ++n) {
        int jb = n0 + (w & 1) * 64 + n * 16 + lr * 4;
        f32x4 bv = *(const f32x4*)&bias[jb];
        f32x4 o;
#pragma unroll
        for (int r = 0; r < 4; ++r) o[r] = acc[m][n][r] + bv[r];
        *(f32x4*)&Cout[(size_t)i * D_ + jb] = o;
      }
    }
  } else if (!vband) {
#pragma unroll
    for (int m = 0; m < 4; ++m) {
      int i = m0 + (w >> 1) * 64 + m * 16 + lc;
      if (i >= MTOK) continue;
      int b = i / S_, s = i - b * S_;
      int stK = s >> 5, nfs = (s >> 4) & 1, lisK = s & 15;
#pragma unroll
      for (int n = 0; n < 4; ++n) {
        int jb = n0 + (w & 1) * 64 + n * 16 + lr * 4;
        f32x4 bv = *(const f32x4*)&bias[jb];
        uint64_t pk = 0;
#pragma unroll
        for (int r = 0; r < 4; ++r)
          pk |= (uint64_t)f2bf(acc[m][n][r] + bv[r]) << (16 * r);
        int which = jb >> 9, h = (jb >> 8) & 1, d = jb & 255;
        int bh = b * H_ + h;
        if (which == 0) {
          *(uint64_t*)&Qb[(size_t)(bh * SPAD + s) * HD_ + d] = pk;
        } else {
          *(uint64_t*)&Kf[(((size_t)(bh * NKT + stK)) * 16 + (d >> 5) * 2 + nfs) * 512 +
                          (((d >> 3) & 3) * 16 + lisK) * 8 + (d & 7)] = pk;
        }
      }
    }
  } else {
    int jv[4]; float bj[4];
#pragma unroll
    for (int n = 0; n < 4; ++n) { jv[n] = n0 + (w & 1) * 64 + n * 16 + lc; bj[n] = bias[jv[n]]; }
#pragma unroll
    for (int m = 0; m < 4; ++m) {
#pragma unroll
      for (int rp = 0; rp < 4; rp += 2) {
        int i0 = m0 + (w >> 1) * 64 + m * 16 + lr * 4 + rp;
        if (i0 >= MTOK) continue;
        int b = i0 / S_, s = i0 - b * S_;
        int stK = s >> 5, lvhi = (s >> 3) & 3, es = s & 7;
#pragma unroll
        for (int n = 0; n < 4; ++n) {
          int j = jv[n];
          int h = (j >> 8) & 1, d = j & 255;
          int bh = b * H_ + h;
          u32 pk = (u32)f2bf(acc[m][n][rp] + bj[n]) |
                   ((u32)f2bf(acc[m][n][rp + 1] + bj[n]) << 16);
          *(u32*)&Vf[(((size_t)(bh * NKT + stK)) * 16 + (d >> 4)) * 512 +
                     (lvhi * 16 + (d & 15)) * 8 + es] = pk;
        }
      }
    }
  }
}

// ---------------------------------------------------------------------------
// Kernel 3: causal flash attention v14 = v12 per-tile code + GRID-LEVEL
// KV-SPLIT for qt >= QSPLIT: two independent blocks (lo tiles [0,lo_n),
// hi tiles [lo_n,nkv), both counts even) write raw bf16 partials (O,m,l);
// combine_kernel merges. Unsplit (qt < QSPLIT) path identical to v12.
// Longest block 38 -> 20 iters; wall moves to throughput bound (~24 iters).
// ---------------------------------------------------------------------------
__global__ __launch_bounds__(256, 2) void attn_kernel(
    const u16* __restrict__ Qb, const u16* __restrict__ Kf,
    const u16* __restrict__ Vf, u16* __restrict__ Obf,
    u16* __restrict__ Opart, float* __restrict__ ML)
{
  __shared__ u16 ldsK[2][16 * 512];     // 2 x 16 KiB, frag = kb*2+nf
  __shared__ u16 ldsP[4][16 * 36];      // per-wave P [16 q][32 kv], pad 36

  const int id   = blockIdx.x;          // 0..895
  const int xcd  = id & 7;
  const int slot = id >> 3;             // 0..111
  const int bh   = xcd + 8 * (slot / 28);
  const int u    = slot % 28;           // 0..27 (18 split halves + 10 unsplit)
  int qt, half, st0, endk;
  if (u < 18) {                         // split blocks, longest first
    qt   = 18 - (u >> 1);
    half = u & 1;
    int nkv = 2 * qt + 2;
    int lo  = (qt + 2) & ~1;            // even lo count; hi = nkv-lo also even
    st0  = half ? lo : 0;
    endk = half ? nkv : lo;
  } else {                              // unsplit, qt 9..0
    qt   = 9 - (u - 18);
    half = -1;
    st0  = 0;
    endk = 2 * qt + 2;
  }
  const int q0 = qt * 64;
  const int t  = threadIdx.x, l = t & 63, w = t >> 6;
  const int lr = l >> 4, lc = l & 15;
  const int wq0 = q0 + w * 16;
  const int qrow_l = wq0 + lc;

  // Q fragments (B-operand rows=q over d): 8 d-blocks of 32
  bf16x8 qf[8];
  const u16* qbase = Qb + (size_t)(bh * SPAD + qrow_l) * HD_ + lr * 8;
#pragma unroll
  for (int kb = 0; kb < 8; ++kb)
    qf[kb] = *(const bf16x8*)(qbase + kb * 32);

  f32x4 oacc[16] = {};
  float mrow = -1e30f, lsum = 0.f;

  const u16* kroot = Kf + ((size_t)(bh * NKT) * 16 + w) * 512 + l * 8;
  const u16* vroot = Vf + ((size_t)(bh * NKT) * 16) * 512 + l * 8;

  // prologue: stage K(st0)->buf0, K(st0+1)->buf1 (st0 even, count >= 2);
  // load V(st0) to registers.
#pragma unroll
  for (int c = 0; c < 4; ++c) {
    async_copy16(&ldsK[0][(c * 4 + w) * 512], kroot + (size_t)st0 * 8192 + c * 2048);
    async_copy16(&ldsK[1][(c * 4 + w) * 512], kroot + (size_t)(st0 + 1) * 8192 + c * 2048);
  }
  bf16x8 vfr[16];
#pragma unroll
  for (int f = 0; f < 16; ++f)
    vfr[f] = *(const bf16x8*)(vroot + (size_t)st0 * 8192 + f * 512);
  __syncthreads();

  f32x4 saccA[2] = {}, saccB[2] = {};
  // QK(st0) -> saccA (buf0 since st0 even)
  __builtin_amdgcn_s_setprio(1);
#pragma unroll
  for (int kb = 0; kb < 8; ++kb)
#pragma unroll
    for (int nf = 0; nf < 2; ++nf) {
      bf16x8 kf = *(bf16x8*)&ldsK[0][((kb * 2 + nf) * 64 + l) * 8];
      saccA[nf] = __builtin_amdgcn_mfma_f32_16x16x32_bf16(kf, qf[kb], saccA[nf], 0, 0, 0);
    }
  __builtin_amdgcn_s_setprio(0);
  __syncthreads();   // all waves past QK(st0) before buf0 restage in sub-iter 0

#define SUBITER(J, S, N)                                                       \
  {                                                                            \
    const int j_ = (J);                                                        \
    if (j_ + 2 < endk) {                                                       \
      const u16* kb_ = kroot + (size_t)(j_ + 2) * 8192;                        \
      _Pragma("unroll")                                                        \
      for (int c = 0; c < 4; ++c)                                              \
        async_copy16(&ldsK[j_ & 1][(c * 4 + w) * 512], kb_ + c * 2048);        \
    }                                                                          \
    const int kv0 = j_ * 32;                                                   \
    float sv[2][4];                                                            \
    float pm = -1e30f;                                                         \
    if (kv0 + 31 <= wq0) {                                                     \
      _Pragma("unroll")                                                        \
      for (int nf = 0; nf < 2; ++nf)                                           \
        _Pragma("unroll")                                                      \
        for (int r = 0; r < 4; ++r) {                                          \
          float v = S[nf][r] * 0.0625f;                                        \
          sv[nf][r] = v;                                                       \
          pm = fmaxf(pm, v);                                                   \
        }                                                                      \
    } else {                                                                   \
      _Pragma("unroll")                                                        \
      for (int nf = 0; nf < 2; ++nf)                                           \
        _Pragma("unroll")                                                      \
        for (int r = 0; r < 4; ++r) {                                          \
          int kvi = kv0 + nf * 16 + lr * 4 + r;                                \
          float v = ((kvi <= qrow_l) && (kvi < S_)) ? S[nf][r] * 0.0625f       \
                                                    : -1e30f;                  \
          sv[nf][r] = v;                                                       \
          pm = fmaxf(pm, v);                                                   \
        }                                                                      \
    }                                                                          \
    pm = fmaxf(pm, __shfl_xor(pm, 16));                                        \
    pm = fmaxf(pm, __shfl_xor(pm, 32));                                        \
    bool skip = (pm <= mrow + 8.0f);                                           \
    if (!__all(skip)) {                                                        \
      float mn = fmaxf(mrow, pm);                                              \
      float sc = exp2f((mrow - mn) * LOG2E);                                   \
      mrow = mn;                                                               \
      lsum *= sc;                                                              \
      _Pragma("unroll")                                                        \
      for (int nf = 0; nf < 16; ++nf)                                          \
        _Pragma("unroll")                                                      \
        for (int r = 0; r < 4; ++r) oacc[nf][r] *= sc;                         \
    }                                                                          \
    _Pragma("unroll")                                                          \
    for (int nf = 0; nf < 2; ++nf) {                                           \
      float p0 = exp2f((sv[nf][0] - mrow) * LOG2E);                            \
      float p1 = exp2f((sv[nf][1] - mrow) * LOG2E);                            \
      float p2 = exp2f((sv[nf][2] - mrow) * LOG2E);                            \
      float p3 = exp2f((sv[nf][3] - mrow) * LOG2E);                            \
      lsum += (p0 + p1) + (p2 + p3);                                           \
      uint64_t pk = (uint64_t)f2bf(p0) | ((uint64_t)f2bf(p1) << 16) |          \
                    ((uint64_t)f2bf(p2) << 32) | ((uint64_t)f2bf(p3) << 48);   \
      *(uint64_t*)&ldsP[w][lc * 36 + nf * 16 + lr * 4] = pk;                   \
    }                                                                          \
    if (j_ + 1 < endk) {                                                       \
      N[0] = (f32x4){0.f, 0.f, 0.f, 0.f};                                      \
      N[1] = (f32x4){0.f, 0.f, 0.f, 0.f};                                      \
      __builtin_amdgcn_s_setprio(1);                                           \
      _Pragma("unroll")                                                        \
      for (int kb = 0; kb < 8; ++kb)                                           \
        _Pragma("unroll")                                                      \
        for (int nf = 0; nf < 2; ++nf) {                                       \
          bf16x8 kf =                                                          \
              *(bf16x8*)&ldsK[(j_ + 1) & 1][((kb * 2 + nf) * 64 + l) * 8];     \
          N[nf] = __builtin_amdgcn_mfma_f32_16x16x32_bf16(kf, qf[kb], N[nf],   \
                                                          0, 0, 0);            \
        }                                                                      \
      __builtin_amdgcn_s_setprio(0);                                           \
    }                                                                          \
    __syncthreads();                                                           \
    bf16x8 pf = *(bf16x8*)&ldsP[w][lc * 36 + lr * 8];                          \
    __builtin_amdgcn_s_setprio(1);                                             \
    _Pragma("unroll")                                                          \
    for (int nf = 0; nf < 16; ++nf)                                            \
      oacc[nf] =                                                               \
          __builtin_amdgcn_mfma_f32_16x16x32_bf16(vfr[nf], pf, oacc[nf],       \
                                                  0, 0, 0);                    \
    __builtin_amdgcn_s_setprio(0);                                             \
    if (j_ + 1 < endk) {                                                       \
      const u16* vb_ = vroot + (size_t)(j_ + 1) * 8192;                        \
      _Pragma("unroll")                                                        \
      for (int f = 0; f < 16; ++f) vfr[f] = *(const bf16x8*)(vb_ + f * 512);   \
    }                                                                          \
  }

  for (int kt = st0; kt < endk; kt += 2) {
    SUBITER(kt, saccA, saccB);
    SUBITER(kt + 1, saccB, saccA);
  }
#undef SUBITER

  // row sum across the 4 kv-quarter lanes
  float s = lsum;
  s += __shfl_xor(s, 16);
  s += __shfl_xor(s, 32);

  if (half < 0) {
    // unsplit: normalize + packed Obf write (frag-major)
    float inv = 1.0f / s;
    const int b = bh >> 1, h = bh & 1;
    if (qrow_l < S_) {
      int i = b * S_ + qrow_l;
      int it = i >> 7, mf = (i >> 4) & 7, li = i & 15;
#pragma unroll
      for (int nf = 0; nf < 16; ++nf) {
        int j0 = h * HD_ + nf * 16 + lr * 4;
        uint64_t pk = 0;
#pragma unroll
        for (int r = 0; r < 4; ++r)
          pk |= (uint64_t)f2bf(oacc[nf][r] * inv) << (16 * r);
        size_t addr = (((size_t)(it * 8 + (j0 >> 6))) * 16 + ((j0 >> 5) & 1) * 8 + mf) * 512 +
                      (((j0 >> 3) & 3) * 16 + li) * 8 + (j0 & 7);
        *(uint64_t*)&Obf[addr] = pk;
      }
    }
  } else {
    // split: write RAW partials (bf16 O, f32 m/l) for combine_kernel
    int rowl = ((bh * NSQT) + (qt - QSPLIT)) * 64 + w * 16 + lc;   // 0..NSROW-1
    size_t robase = ((size_t)(half ? NSROW : 0) + rowl) * 256;
#pragma unroll
    for (int nf = 0; nf < 16; ++nf) {
      uint64_t pk = 0;
#pragma unroll
      for (int r = 0; r < 4; ++r)
        pk |= (uint64_t)f2bf(oacc[nf][r]) << (16 * r);
      *(uint64_t*)&Opart[robase + nf * 16 + lr * 4] = pk;
    }
    if (l < 16) {
      int rml = ((bh * NSQT) + (qt - QSPLIT)) * 64 + w * 16 + l;
      ML[(((half ? NSROW : 0) + rml)) * 2]     = mrow;
      ML[(((half ? NSROW : 0) + rml)) * 2 + 1] = s;
    }
  }
}

// ---------------------------------------------------------------------------
// Kernel 4: combine split partials: O = (a1*O1 + a2*O2)/(a1*l1 + a2*l2),
// ai = e^(mi - m). All-masked halves wash out (a = 0 exactly).
// Thread = (split row, 8-d group). Writes Obf frag-major (16B contiguous).
// ---------------------------------------------------------------------------
__global__ void combine_kernel(const u16* __restrict__ Opart,
                               const float* __restrict__ ML,
                               u16* __restrict__ Obf) {
  int g = blockIdx.x * 256 + threadIdx.x;     // 0 .. NSROW*32-1
  if (g >= NSROW * 32) return;
  int row = g >> 5, dg = g & 31;
  int bh = row / (NSQT * 64), rem = row % (NSQT * 64);
  int qt = QSPLIT + rem / 64, qr = rem & 63;
  int qrow = qt * 64 + qr;
  if (qrow >= S_) return;

  float m1 = ML[row * 2],           l1 = ML[row * 2 + 1];
  float m2 = ML[(NSROW + row) * 2], l2 = ML[(NSROW + row) * 2 + 1];
  float m  = fmaxf(m1, m2);
  float a1 = exp2f((m1 - m) * LOG2E);
  float a2 = exp2f((m2 - m) * LOG2E);
  float inv = 1.0f / (a1 * l1 + a2 * l2);

  bf16x8 o1 = *(const bf16x8*)&Opart[((size_t)row) * 256 + dg * 8];
  bf16x8 o2 = *(const bf16x8*)&Opart[((size_t)(NSROW + row)) * 256 + dg * 8];
  bf16x8 o;
#pragma unroll
  for (int e = 0; e < 8; ++e)
    o[e] = (short)f2bf((a1 * bf2f((u16)o1[e]) + a2 * bf2f((u16)o2[e])) * inv);

  int b = bh >> 1, h = bh & 1;
  int i = b * S_ + qrow;
  int j0 = h * HD_ + dg * 8;
  int it = i >> 7, mf = (i >> 4) & 7, li = i & 15;
  size_t addr = (((size_t)(it * 8 + (j0 >> 6))) * 16 + ((j0 >> 5) & 1) * 8 + mf) * 512 +
                (((j0 >> 3) & 3) * 16 + li) * 8;
  *(bf16x8*)&Obf[addr] = o;
}

// ---------------------------------------------------------------------------
extern "C" void kernel_launch(void* const* d_in, const int* in_sizes, int n_in,
                              void* d_out, int out_size, void* d_ws, size_t ws_size,
                              hipStream_t stream) {
  const float* X    = (const float*)d_in[0];
  const float* Wqkv = (const float*)d_in[1];
  const float* bqkv = (const float*)d_in[2];
  const float* Wout = (const float*)d_in[3];
  const float* bout = (const float*)d_in[4];
  float* out = (float*)d_out;

  char* ws = (char*)d_ws;
  u16* Xf  = (u16*)ws;  ws += (size_t)MPAD * D_ * 2;     // 19.66 MB
  u16* Wqf = (u16*)ws;  ws += (size_t)NQKV * D_ * 2;     // 1.57 MB
  u16* Wof = (u16*)ws;  ws += (size_t)D_ * D_ * 2;
  u16* Qb  = (u16*)ws;  ws += (size_t)B_ * H_ * SPAD * HD_ * 2;
  u16* Kf  = (u16*)ws;  ws += (size_t)B_ * H_ * SPAD * HD_ * 2;
  u16* Vf  = (u16*)ws;  ws += (size_t)B_ * H_ * SPAD * HD_ * 2;
  u16* Obf = (u16*)ws;  ws += (size_t)MPAD * D_ * 2;
  // Aliases (dead after gemm<0>; stream order protects):
  u16*   Opart = Xf;               // 2*NSROW*256*2B = 18.87 MB < 19.66 MB
  float* MLb   = (float*)Wqf;      // 2*NSROW*2*4B  = 0.29 MB  < 1.57 MB

  convert_kernel<<<2048, 256, 0, stream>>>(X, Wqkv, Wout, Xf, Wqf, Wof);
  gemm_kernel<0><<<1800, 256, 0, stream>>>(Xf, Wqf, bqkv, 12, Qb, Kf, Vf, nullptr);
  attn_kernel<<<896, 256, 0, stream>>>(Qb, Kf, Vf, Obf, Opart, MLb);
  combine_kernel<<<(NSROW * 32 + 255) / 256, 256, 0, stream>>>(Opart, MLb, Obf);
  gemm_kernel<1><<<600, 256, 0, stream>>>(Obf, Wof, bout, 4, nullptr, nullptr, nullptr, out);
}

// Round 21
// 146.892 us; speedup vs baseline: 1.0694x; 1.0694x over previous
//
#include <hip/hip_runtime.h>
#include <stdint.h>

#define D_    512
#define H_    2
#define HD_   256
#define B_    16
#define S_    1194
#define MTOK  19104          // B_*S_  (even; batch boundaries at even i)
#define MPAD  19200          // 150*128
#define SPAD  1216           // 19*64 = 38*32
#define NQKV  1536
#define NKT   38             // kv tiles of 32 (global layout granularity)
#define LOG2E 1.44269504088896340736f

typedef unsigned short u16;
typedef unsigned int u32;
typedef __attribute__((ext_vector_type(8))) short bf16x8;   // 8 bf16 = 4 VGPR
typedef __attribute__((ext_vector_type(4))) float f32x4;

__device__ inline u16 f2bf(float x) {
  union { float f; unsigned u; } c; c.f = x;
  unsigned r = c.u + 0x7fffu + ((c.u >> 16) & 1u);  // RNE
  return (u16)(r >> 16);
}

// async global->LDS, 16B per lane. LDS dest is wave-uniform base (HW adds
// lane*16); global src per-lane, CONTIGUOUS: 1 instr = 1KB sequential.
__device__ inline void async_copy16(void* lds, const void* g) {
  __builtin_amdgcn_global_load_lds(
      (__attribute__((address_space(1))) void*)(g),
      (__attribute__((address_space(3))) void*)(lds),
      16, 0, 0);
}

// ---------------------------------------------------------------------------
// Kernel 1: X/W -> frag-major bf16.
// ---------------------------------------------------------------------------
__global__ void convert_kernel(const float* __restrict__ X,
                               const float* __restrict__ Wqkv,
                               const float* __restrict__ Wout,
                               u16* __restrict__ Xf,
                               u16* __restrict__ Wqf,
                               u16* __restrict__ Wof) {
  const int NXG = MPAD * 64;
  const int NQG = 12 * 8 * 16 * 64;
  const int NOG = 4 * 8 * 16 * 64;
  const int TOT = NXG + NQG + NOG;
  int stride = gridDim.x * blockDim.x;
  for (int g = blockIdx.x * blockDim.x + threadIdx.x; g < TOT; g += stride) {
    if (g < NXG) {
      int lane = g & 63, f = (g >> 6) & 15, kt = (g >> 10) & 7, mt = g >> 13;
      int i = mt * 128 + (f & 7) * 16 + (lane & 15);
      int k = kt * 64 + (f >> 3) * 32 + (lane >> 4) * 8;
      bf16x8 o;
      if (i < MTOK) {
        f32x4 v0 = *(const f32x4*)&X[(size_t)i * 512 + k];
        f32x4 v1 = *(const f32x4*)&X[(size_t)i * 512 + k + 4];
#pragma unroll
        for (int e = 0; e < 4; ++e) { o[e] = (short)f2bf(v0[e]); o[4 + e] = (short)f2bf(v1[e]); }
      } else {
#pragma unroll
        for (int e = 0; e < 8; ++e) o[e] = 0;
      }
      *(bf16x8*)&Xf[(size_t)g * 8] = o;
    } else if (g < NXG + NQG) {
      int gg = g - NXG;
      int lane = gg & 63, f = (gg >> 6) & 15, kt = (gg >> 10) & 7, nt = gg >> 13;
      int j = nt * 128 + (f & 7) * 16 + (lane & 15);
      int k = kt * 64 + (f >> 3) * 32 + (lane >> 4) * 8;
      bf16x8 o;
#pragma unroll
      for (int e = 0; e < 8; ++e) o[e] = (short)f2bf(Wqkv[(size_t)(k + e) * NQKV + j]);
      *(bf16x8*)&Wqf[(size_t)gg * 8] = o;
    } else {
      int gg = g - NXG - NQG;
      int lane = gg & 63, f = (gg >> 6) & 15, kt = (gg >> 10) & 7, nt = gg >> 13;
      int j = nt * 128 + (f & 7) * 16 + (lane & 15);
      int k = kt * 64 + (f >> 3) * 32 + (lane >> 4) * 8;
      bf16x8 o;
#pragma unroll
      for (int e = 0; e < 8; ++e) o[e] = (short)f2bf(Wout[(size_t)(k + e) * 512 + j]);
      *(bf16x8*)&Wof[(size_t)gg * 8] = o;
    }
  }
}

// ---------------------------------------------------------------------------
// GEMM v3: m97 single-buffer schedule + vectorized epilogue.
// ---------------------------------------------------------------------------
template<int MODE>
__global__ __launch_bounds__(256, 2) void gemm_kernel(
    const u16* __restrict__ Af, const u16* __restrict__ Bf,
    const float* __restrict__ bias, int nb,
    u16* __restrict__ Qb, u16* __restrict__ Kf, u16* __restrict__ Vf,
    float* __restrict__ Cout)
{
  __shared__ u16 ldsA[16 * 512];       // 16 KiB (single buffer)
  __shared__ u16 ldsB[16 * 512];

  const int t  = threadIdx.x;
  const int l  = t & 63;
  const int w  = t >> 6;
  const int lr = l >> 4, lc = l & 15;

  const int nwg = gridDim.x;
  const int qq = nwg >> 3, rr8 = nwg & 7;
  const int xcd = blockIdx.x & 7, off = blockIdx.x >> 3;
  const int wgid = (xcd < rr8 ? xcd * (qq + 1) : rr8 * (qq + 1) + (xcd - rr8) * qq) + off;
  const int m0 = (wgid / nb) * 128;
  const int n0 = (wgid % nb) * 128;
  const bool vband = (MODE == 0) && ((wgid % nb) >= 8);

  const u16* pA = Af + ((size_t)(m0 >> 7) * 128 + w) * 512 + l * 8;
  const u16* pB = Bf + ((size_t)(n0 >> 7) * 128 + w) * 512 + l * 8;

  f32x4 acc[4][4] = {};

  for (int kt = 0; kt < 8; ++kt) {
    __syncthreads();                   // prev compute done: buffer reusable
    const u16* qA = pA + kt * 8192;
    const u16* qB = pB + kt * 8192;
#pragma unroll
    for (int c = 0; c < 4; ++c) {
      async_copy16(&ldsA[(c * 4 + w) * 512], qA + c * 2048);
      async_copy16(&ldsB[(c * 4 + w) * 512], qB + c * 2048);
    }
    __syncthreads();                   // stage landed (vmcnt drain)
#pragma unroll
    for (int kk = 0; kk < 2; ++kk) {
      bf16x8 af[4], bfr[4];
#pragma unroll
      for (int m = 0; m < 4; ++m)
        af[m] = *(bf16x8*)&ldsA[((kk * 8 + (w >> 1) * 4 + m) * 64 + l) * 8];
#pragma unroll
      for (int n = 0; n < 4; ++n)
        bfr[n] = *(bf16x8*)&ldsB[((kk * 8 + (w & 1) * 4 + n) * 64 + l) * 8];
      __builtin_amdgcn_s_setprio(1);
      if (!vband) {                    // swapped: D^T (lane = fixed token i)
#pragma unroll
        for (int m = 0; m < 4; ++m)
#pragma unroll
          for (int n = 0; n < 4; ++n)
            acc[m][n] = __builtin_amdgcn_mfma_f32_16x16x32_bf16(bfr[n], af[m], acc[m][n], 0, 0, 0);
      } else {                         // original: lane = fixed col j
#pragma unroll
        for (int m = 0; m < 4; ++m)
#pragma unroll
          for (int n = 0; n < 4; ++n)
            acc[m][n] = __builtin_amdgcn_mfma_f32_16x16x32_bf16(af[m], bfr[n], acc[m][n], 0, 0, 0);
      }
      __builtin_amdgcn_s_setprio(0);
    }
  }

  if (MODE == 1) {
#pragma unroll
    for (int m = 0; m < 4; ++m) {
      int i = m0 + (w >> 1) * 64 + m * 16 + lc;
      if (i >= MTOK) continue;
#pragma unroll
      for (int n = 0; n < 4; ++n) {
        int jb = n0 + (w & 1) * 64 + n * 16 + lr * 4;
        f32x4 bv = *(const f32x4*)&bias[jb];
        f32x4 o;
#pragma unroll
        for (int r = 0; r < 4; ++r) o[r] = acc[m][n][r] + bv[r];
        *(f32x4*)&Cout[(size_t)i * D_ + jb] = o;
      }
    }
  } else if (!vband) {
#pragma unroll
    for (int m = 0; m < 4; ++m) {
      int i = m0 + (w >> 1) * 64 + m * 16 + lc;
      if (i >= MTOK) continue;
      int b = i / S_, s = i - b * S_;
      int stK = s >> 5, nfs = (s >> 4) & 1, lisK = s & 15;
#pragma unroll
      for (int n = 0; n < 4; ++n) {
        int jb = n0 + (w & 1) * 64 + n * 16 + lr * 4;
        f32x4 bv = *(const f32x4*)&bias[jb];
        uint64_t pk = 0;
#pragma unroll
        for (int r = 0; r < 4; ++r)
          pk |= (uint64_t)f2bf(acc[m][n][r] + bv[r]) << (16 * r);
        int which = jb >> 9, h = (jb >> 8) & 1, d = jb & 255;
        int bh = b * H_ + h;
        if (which == 0) {
          *(uint64_t*)&Qb[(size_t)(bh * SPAD + s) * HD_ + d] = pk;
        } else {
          *(uint64_t*)&Kf[(((size_t)(bh * NKT + stK)) * 16 + (d >> 5) * 2 + nfs) * 512 +
                          (((d >> 3) & 3) * 16 + lisK) * 8 + (d & 7)] = pk;
        }
      }
    }
  } else {
    int jv[4]; float bj[4];
#pragma unroll
    for (int n = 0; n < 4; ++n) { jv[n] = n0 + (w & 1) * 64 + n * 16 + lc; bj[n] = bias[jv[n]]; }
#pragma unroll
    for (int m = 0; m < 4; ++m) {
#pragma unroll
      for (int rp = 0; rp < 4; rp += 2) {
        int i0 = m0 + (w >> 1) * 64 + m * 16 + lr * 4 + rp;   // even
        if (i0 >= MTOK) continue;                             // i0+1 < MTOK too
        int b = i0 / S_, s = i0 - b * S_;                     // pair same batch
        int stK = s >> 5, lvhi = (s >> 3) & 3, es = s & 7;    // es even
#pragma unroll
        for (int n = 0; n < 4; ++n) {
          int j = jv[n];
          int h = (j >> 8) & 1, d = j & 255;
          int bh = b * H_ + h;
          u32 pk = (u32)f2bf(acc[m][n][rp] + bj[n]) |
                   ((u32)f2bf(acc[m][n][rp + 1] + bj[n]) << 16);
          *(u32*)&Vf[(((size_t)(bh * NKT + stK)) * 16 + (d >> 4)) * 512 +
                     (lvhi * 16 + (d & 15)) * 8 + es] = pk;
        }
      }
    }
  }
}

// ---------------------------------------------------------------------------
// Kernel 3: causal flash attention v12 (champion): swapped-operand softmax,
// K LDS-dbuf prefetch dist 2, V direct-to-reg prefetch dist 1, defer-max,
// packed P/output stores.
// ---------------------------------------------------------------------------
__global__ __launch_bounds__(256, 2) void attn_kernel(
    const u16* __restrict__ Qb, const u16* __restrict__ Kf,
    const u16* __restrict__ Vf, u16* __restrict__ Obf)
{
  __shared__ u16 ldsK[2][16 * 512];     // 2 x 16 KiB, frag = kb*2+nf
  __shared__ u16 ldsP[4][16 * 36];      // per-wave P [16 q][32 kv], pad 36

  const int id   = blockIdx.x;          // 0..607
  const int xcd  = id & 7;
  const int slot = id >> 3;             // 0..75
  const int bh   = xcd + 8 * (slot / 19);
  const int qt   = 18 - (slot % 19);    // long blocks first
  const int q0   = qt * 64;
  const int nkv  = 2 * qt + 2;          // kv tiles of 32 (ALWAYS EVEN)
  const int t  = threadIdx.x, l = t & 63, w = t >> 6;
  const int lr = l >> 4, lc = l & 15;
  const int wq0 = q0 + w * 16;          // wave's first q row
  const int qrow_l = wq0 + lc;          // THIS lane's q row (swapped space)

  // Q fragments (B-operand rows=q over d): 8 d-blocks of 32
  bf16x8 qf[8];
  const u16* qbase = Qb + (size_t)(bh * SPAD + qrow_l) * HD_ + lr * 8;
#pragma unroll
  for (int kb = 0; kb < 8; ++kb)
    qf[kb] = *(const bf16x8*)(qbase + kb * 32);

  f32x4 oacc[16] = {};                  // [d-block]; col=q=lc, reg=d-sub
  float mrow = -1e30f, lsum = 0.f;      // per-lane scalars (q = lc)

  const u16* kroot = Kf + ((size_t)(bh * NKT) * 16 + w) * 512 + l * 8;
  const u16* vroot = Vf + ((size_t)(bh * NKT) * 16) * 512 + l * 8;

  // prologue: stage K(0)->buf0, K(1)->buf1; load V(0) to registers
#pragma unroll
  for (int c = 0; c < 4; ++c) {
    async_copy16(&ldsK[0][(c * 4 + w) * 512], kroot + c * 2048);
    async_copy16(&ldsK[1][(c * 4 + w) * 512], kroot + 8192 + c * 2048);
  }
  bf16x8 vfr[16];
#pragma unroll
  for (int f = 0; f < 16; ++f) vfr[f] = *(const bf16x8*)(vroot + f * 512);
  __syncthreads();

  f32x4 saccA[2] = {}, saccB[2] = {};
  // QK(0) -> saccA
  __builtin_amdgcn_s_setprio(1);
#pragma unroll
  for (int kb = 0; kb < 8; ++kb)
#pragma unroll
    for (int nf = 0; nf < 2; ++nf) {
      bf16x8 kf = *(bf16x8*)&ldsK[0][((kb * 2 + nf) * 64 + l) * 8];
      saccA[nf] = __builtin_amdgcn_mfma_f32_16x16x32_bf16(kf, qf[kb], saccA[nf], 0, 0, 0);
    }
  __builtin_amdgcn_s_setprio(0);
  __syncthreads();   // all waves past QK(0) before buf0 is restaged in sub-iter 0

  // SUBITER(j, S, N): stage K(j+2)->buf[j&1]; softmax(j) on S; QK(j+1)->N;
  // barrier; PV(j) using vfr (loaded last iter); load V(j+1)->vfr.
#define SUBITER(J, S, N)                                                       \
  {                                                                            \
    const int j_ = (J);                                                        \
    if (j_ + 2 < nkv) {                                                        \
      const u16* kb_ = kroot + (size_t)(j_ + 2) * 8192;                        \
      _Pragma("unroll")                                                        \
      for (int c = 0; c < 4; ++c)                                              \
        async_copy16(&ldsK[j_ & 1][(c * 4 + w) * 512], kb_ + c * 2048);        \
    }                                                                          \
    const int kv0 = j_ * 32;                                                   \
    float sv[2][4];                                                            \
    float pm = -1e30f;                                                         \
    if (kv0 + 31 <= wq0) {                                                     \
      _Pragma("unroll")                                                        \
      for (int nf = 0; nf < 2; ++nf)                                           \
        _Pragma("unroll")                                                      \
        for (int r = 0; r < 4; ++r) {                                          \
          float v = S[nf][r] * 0.0625f;                                        \
          sv[nf][r] = v;                                                       \
          pm = fmaxf(pm, v);                                                   \
        }                                                                      \
    } else {                                                                   \
      _Pragma("unroll")                                                        \
      for (int nf = 0; nf < 2; ++nf)                                           \
        _Pragma("unroll")                                                      \
        for (int r = 0; r < 4; ++r) {                                          \
          int kvi = kv0 + nf * 16 + lr * 4 + r;                                \
          float v = ((kvi <= qrow_l) && (kvi < S_)) ? S[nf][r] * 0.0625f       \
                                                    : -1e30f;                  \
          sv[nf][r] = v;                                                       \
          pm = fmaxf(pm, v);                                                   \
        }                                                                      \
    }                                                                          \
    pm = fmaxf(pm, __shfl_xor(pm, 16));                                        \
    pm = fmaxf(pm, __shfl_xor(pm, 32));                                        \
    bool skip = (pm <= mrow + 8.0f);                                           \
    if (!__all(skip)) {                                                        \
      float mn = fmaxf(mrow, pm);                                              \
      float sc = exp2f((mrow - mn) * LOG2E);                                   \
      mrow = mn;                                                               \
      lsum *= sc;                                                              \
      _Pragma("unroll")                                                        \
      for (int nf = 0; nf < 16; ++nf)                                          \
        _Pragma("unroll")                                                      \
        for (int r = 0; r < 4; ++r) oacc[nf][r] *= sc;                         \
    }                                                                          \
    _Pragma("unroll")                                                          \
    for (int nf = 0; nf < 2; ++nf) {                                           \
      float p0 = exp2f((sv[nf][0] - mrow) * LOG2E);                            \
      float p1 = exp2f((sv[nf][1] - mrow) * LOG2E);                            \
      float p2 = exp2f((sv[nf][2] - mrow) * LOG2E);                            \
      float p3 = exp2f((sv[nf][3] - mrow) * LOG2E);                            \
      lsum += (p0 + p1) + (p2 + p3);                                           \
      uint64_t pk = (uint64_t)f2bf(p0) | ((uint64_t)f2bf(p1) << 16) |          \
                    ((uint64_t)f2bf(p2) << 32) | ((uint64_t)f2bf(p3) << 48);   \
      *(uint64_t*)&ldsP[w][lc * 36 + nf * 16 + lr * 4] = pk;                   \
    }                                                                          \
    if (j_ + 1 < nkv) {                                                        \
      N[0] = (f32x4){0.f, 0.f, 0.f, 0.f};                                      \
      N[1] = (f32x4){0.f, 0.f, 0.f, 0.f};                                      \
      __builtin_amdgcn_s_setprio(1);                                           \
      _Pragma("unroll")                                                        \
      for (int kb = 0; kb < 8; ++kb)                                           \
        _Pragma("unroll")                                                      \
        for (int nf = 0; nf < 2; ++nf) {                                       \
          bf16x8 kf =                                                          \
              *(bf16x8*)&ldsK[(j_ + 1) & 1][((kb * 2 + nf) * 64 + l) * 8];     \
          N[nf] = __builtin_amdgcn_mfma_f32_16x16x32_bf16(kf, qf[kb], N[nf],   \
                                                          0, 0, 0);            \
        }                                                                      \
      __builtin_amdgcn_s_setprio(0);                                           \
    }                                                                          \
    __syncthreads();                                                           \
    bf16x8 pf = *(bf16x8*)&ldsP[w][lc * 36 + lr * 8];                          \
    __builtin_amdgcn_s_setprio(1);                                             \
    _Pragma("unroll")                                                          \
    for (int nf = 0; nf < 16; ++nf)                                            \
      oacc[nf] =                                                               \
          __builtin_amdgcn_mfma_f32_16x16x32_bf16(vfr[nf], pf, oacc[nf],       \
                                                  0, 0, 0);                    \
    __builtin_amdgcn_s_setprio(0);                                             \
    if (j_ + 1 < nkv) {                                                        \
      const u16* vb_ = vroot + (size_t)(j_ + 1) * 8192;                        \
      _Pragma("unroll")                                                        \
      for (int f = 0; f < 16; ++f) vfr[f] = *(const bf16x8*)(vb_ + f * 512);   \
    }                                                                          \
  }

  for (int kt = 0; kt < nkv; kt += 2) {
    SUBITER(kt, saccA, saccB);        // softmax(kt); QK(kt+1)->saccB (always)
    SUBITER(kt + 1, saccB, saccA);    // softmax(kt+1); QK(kt+2)->saccA if any
  }
#undef SUBITER

  // finalize (packed u64 stores: 4 consecutive j per r-group)
  float s = lsum;
  s += __shfl_xor(s, 16);
  s += __shfl_xor(s, 32);
  float inv = 1.0f / s;

  const int b = bh >> 1, h = bh & 1;
  if (qrow_l < S_) {
    int i = b * S_ + qrow_l;
    int it = i >> 7, mf = (i >> 4) & 7, li = i & 15;
#pragma unroll
    for (int nf = 0; nf < 16; ++nf) {
      int j0 = h * HD_ + nf * 16 + lr * 4;
      uint64_t pk = 0;
#pragma unroll
      for (int r = 0; r < 4; ++r)
        pk |= (uint64_t)f2bf(oacc[nf][r] * inv) << (16 * r);
      size_t addr = (((size_t)(it * 8 + (j0 >> 6))) * 16 + ((j0 >> 5) & 1) * 8 + mf) * 512 +
                    (((j0 >> 3) & 3) * 16 + li) * 8 + (j0 & 7);
      *(uint64_t*)&Obf[addr] = pk;
    }
  }
}

// ---------------------------------------------------------------------------
extern "C" void kernel_launch(void* const* d_in, const int* in_sizes, int n_in,
                              void* d_out, int out_size, void* d_ws, size_t ws_size,
                              hipStream_t stream) {
  const float* X    = (const float*)d_in[0];
  const float* Wqkv = (const float*)d_in[1];
  const float* bqkv = (const float*)d_in[2];
  const float* Wout = (const float*)d_in[3];
  const float* bout = (const float*)d_in[4];
  float* out = (float*)d_out;

  char* ws = (char*)d_ws;
  u16* Xf  = (u16*)ws;  ws += (size_t)MPAD * D_ * 2;
  u16* Wqf = (u16*)ws;  ws += (size_t)NQKV * D_ * 2;
  u16* Wof = (u16*)ws;  ws += (size_t)D_ * D_ * 2;
  u16* Qb  = (u16*)ws;  ws += (size_t)B_ * H_ * SPAD * HD_ * 2;
  u16* Kf  = (u16*)ws;  ws += (size_t)B_ * H_ * SPAD * HD_ * 2;
  u16* Vf  = (u16*)ws;  ws += (size_t)B_ * H_ * SPAD * HD_ * 2;
  u16* Obf = (u16*)ws;  ws += (size_t)MPAD * D_ * 2;
  // total ~101 MB

  convert_kernel<<<2048, 256, 0, stream>>>(X, Wqkv, Wout, Xf, Wqf, Wof);
  gemm_kernel<0><<<1800, 256, 0, stream>>>(Xf, Wqf, bqkv, 12, Qb, Kf, Vf, nullptr);
  attn_kernel<<<608, 256, 0, stream>>>(Qb, Kf, Vf, Obf);
  gemm_kernel<1><<<600, 256, 0, stream>>>(Obf, Wof, bout, 4, nullptr, nullptr, nullptr, out);
}